// Round 1
// baseline (197.068 us; speedup 1.0000x reference)
//
#include <hip/hip_runtime.h>
#include <hip/hip_bf16.h>

#define BS   2
#define LEN  2048
#define DIM  1024
#define NH   16
#define DHD  64
#define POSD 16
#define DHE  80      // DHD + POSD (V extended with encoding)
#define NTOK 4096    // BS*LEN
#define INW  1040    // DIM + POSD input row width

typedef __attribute__((ext_vector_type(8))) short bf16x8;   // 8 bf16 = 4 VGPR
typedef __attribute__((ext_vector_type(4))) float f32x4;

__device__ __forceinline__ short f2bf(float f) {
    union { float f; unsigned u; } v; v.f = f;
    unsigned r = v.u + 0x7fffu + ((v.u >> 16) & 1u);
    return (short)(r >> 16);
}
__device__ __forceinline__ float bf2f(short s) {
    union { unsigned u; float f; } v; v.u = ((unsigned)(unsigned short)s) << 16;
    return v.f;
}
__device__ __forceinline__ f32x4 mfma16(bf16x8 a, bf16x8 b, f32x4 c) {
    return __builtin_amdgcn_mfma_f32_16x16x32_bf16(a, b, c, 0, 0, 0);
}

// ---------------------------------------------------------------------------
// Kernel 0: convert inputs/weights to bf16, and scatter encoding into Vt rows
// X16: [3][NTOK][DIM] bf16   W16: [4][DIM][DIM] bf16   Vt: [BS][NH][DHE][LEN]
// ---------------------------------------------------------------------------
__global__ __launch_bounds__(256) void prep_kernel(
    const float* __restrict__ qin, const float* __restrict__ kin, const float* __restrict__ vin,
    const float* __restrict__ Wq, const float* __restrict__ Wk,
    const float* __restrict__ Wv, const float* __restrict__ Wo,
    short* __restrict__ X16, short* __restrict__ W16, short* __restrict__ Vt)
{
    const int NA = 3 * NTOK * DIM / 4;   // 3145728 float4 items
    const int NW = 4 * DIM * DIM / 4;    // 1048576 float4 items
    int idx = blockIdx.x * 256 + threadIdx.x;
    if (idx < NA) {
        int per = NTOK * DIM / 4;
        int mi = idx / per, r = idx % per;
        int tok = r >> 8, c4 = r & 255;           // 256 float4 per row
        const float* src = (mi == 0 ? qin : (mi == 1 ? kin : vin));
        float4 v = *(const float4*)(src + (size_t)tok * INW + c4 * 4);
        short4 o;
        o.x = f2bf(v.x); o.y = f2bf(v.y); o.z = f2bf(v.z); o.w = f2bf(v.w);
        *(short4*)(X16 + (size_t)mi * NTOK * DIM + (size_t)tok * DIM + c4 * 4) = o;
        return;
    }
    idx -= NA;
    if (idx < NW) {
        int wi = idx >> 18, r = idx & 262143;     // DIM*DIM/4 = 2^18
        const float* w = (wi == 0 ? Wq : (wi == 1 ? Wk : (wi == 2 ? Wv : Wo)));
        float4 v = *(const float4*)(w + (size_t)r * 4);
        short4 o;
        o.x = f2bf(v.x); o.y = f2bf(v.y); o.z = f2bf(v.z); o.w = f2bf(v.w);
        *(short4*)(W16 + (size_t)wi * DIM * DIM + (size_t)r * 4) = o;
        return;
    }
    idx -= NW;
    // encoding: Vt[b][h][64+p][l] = bf16(kin[b][l][1024+p]); item = 8 l's
    if (idx < BS * NH * POSD * (LEN / 8)) {
        int l8 = idx & 255;
        int p  = (idx >> 8) & 15;
        int h  = (idx >> 12) & 15;
        int b  = (idx >> 16);
        int l0 = l8 * 8;
        bf16x8 o;
        for (int i = 0; i < 8; i++)
            o[i] = f2bf(kin[(size_t)(b * LEN + l0 + i) * INW + DIM + p]);
        *(bf16x8*)(Vt + ((size_t)(b * NH + h) * DHE + DHD + p) * LEN + l0) = o;
    }
}

// ---------------------------------------------------------------------------
// Kernel 1: fused QKV projection GEMM.  Y = X @ W^T + b  (Q pre-scaled 1/8)
// 128x128 tile, BK=32, 4 waves (2x2), 16x16x32 MFMA.
// Outputs: Qb/Kb: [BS][NH][LEN][DHD]  Vt: [BS][NH][DHE][LEN] (rows 0..63)
// ---------------------------------------------------------------------------
__global__ __launch_bounds__(256) void qkv_gemm(
    const short* __restrict__ X16, const short* __restrict__ W16,
    const float* __restrict__ bq, const float* __restrict__ bk, const float* __restrict__ bv,
    short* __restrict__ Qb, short* __restrict__ Kb, short* __restrict__ Vt)
{
    __shared__ short As[128 * 32];
    __shared__ short Bs[128 * 32];
    int bid = blockIdx.x;
    int nt = bid % 24, mt = bid / 24;
    int mat = nt >> 3, ntl = nt & 7;
    const short* A = X16 + (size_t)mat * NTOK * DIM;
    const short* W = W16 + (size_t)mat * DIM * DIM;

    int t = threadIdx.x;
    int w = t >> 6, lane = t & 63, g = lane >> 4, c = lane & 15;
    int wr = w >> 1, wc = w & 1;

    f32x4 acc[4][4];
    for (int i = 0; i < 4; i++) for (int j = 0; j < 4; j++)
        acc[i][j] = (f32x4){0.f, 0.f, 0.f, 0.f};

    int sr = t >> 1, sh = t & 1;
    const short* aSrc = A + (size_t)(mt * 128 + sr) * DIM + sh * 16;
    const short* bSrc = W + (size_t)(ntl * 128 + sr) * DIM + sh * 16;
    int swz = (sr >> 1) & 3;
    int wO0 = sr * 32 + (((sh * 2) ^ swz) * 8);
    int wO1 = sr * 32 + (((sh * 2 + 1) ^ swz) * 8);

    for (int k0 = 0; k0 < DIM; k0 += 32) {
        bf16x8 av0 = *(const bf16x8*)(aSrc + k0);
        bf16x8 av1 = *(const bf16x8*)(aSrc + k0 + 8);
        bf16x8 bv0 = *(const bf16x8*)(bSrc + k0);
        bf16x8 bv1 = *(const bf16x8*)(bSrc + k0 + 8);
        __syncthreads();
        *(bf16x8*)(As + wO0) = av0;
        *(bf16x8*)(As + wO1) = av1;
        *(bf16x8*)(Bs + wO0) = bv0;
        *(bf16x8*)(Bs + wO1) = bv1;
        __syncthreads();
        bf16x8 af[4], bfg[4];
        #pragma unroll
        for (int fm = 0; fm < 4; fm++) {
            int row = wr * 64 + fm * 16 + c;
            af[fm] = *(const bf16x8*)(As + row * 32 + ((g ^ ((row >> 1) & 3)) * 8));
        }
        #pragma unroll
        for (int fn = 0; fn < 4; fn++) {
            int row = wc * 64 + fn * 16 + c;
            bfg[fn] = *(const bf16x8*)(Bs + row * 32 + ((g ^ ((row >> 1) & 3)) * 8));
        }
        #pragma unroll
        for (int fm = 0; fm < 4; fm++)
            #pragma unroll
            for (int fn = 0; fn < 4; fn++)
                acc[fm][fn] = mfma16(af[fm], bfg[fn], acc[fm][fn]);
    }

    const float* bias = (mat == 0 ? bq : (mat == 1 ? bk : bv));
    float qs = (mat == 0) ? 0.125f : 1.0f;   // fold 1/SCALE into Q
    #pragma unroll
    for (int fn = 0; fn < 4; fn++) {
        int n = ntl * 128 + wc * 64 + fn * 16 + c;   // 0..1023 within matrix
        float bval = bias[n];
        int h = n >> 6, dh = n & 63;
        #pragma unroll
        for (int fm = 0; fm < 4; fm++) {
            int mbase = mt * 128 + wr * 64 + fm * 16 + g * 4;
            #pragma unroll
            for (int i = 0; i < 4; i++) {
                int m = mbase + i;
                int b_ = m >> 11, l = m & 2047;
                short yb = f2bf((acc[fm][fn][i] + bval) * qs);
                if (mat == 2)
                    Vt[((size_t)(b_ * NH + h) * DHE + dh) * LEN + l] = yb;
                else if (mat == 0)
                    Qb[((size_t)(b_ * NH + h) * LEN + l) * DHD + dh] = yb;
                else
                    Kb[((size_t)(b_ * NH + h) * LEN + l) * DHD + dh] = yb;
            }
        }
    }
}

// ---------------------------------------------------------------------------
// Kernel 2: causal flash attention, DHE=80 (V carries encoding in dims 64..79)
// 4 waves, q-tile 64 (16 rows/wave), kv-tile 64. Ctx: [BS][NH][LEN][DHE] bf16
// ---------------------------------------------------------------------------
__global__ __launch_bounds__(256) void attn_kernel(
    const short* __restrict__ Qb, const short* __restrict__ Kb,
    const short* __restrict__ Vt, short* __restrict__ Ctx)
{
    __shared__ short Ks[64 * 64];        // [kv][dh], 16B-block xor swizzle
    __shared__ short Vs[DHE * 64];       // [d][kv],  16B-block xor swizzle
    __shared__ short Ps[4][16 * 72];     // per-wave P, padded stride 72

    int bid = blockIdx.x;
    int bh = bid & 31, qt = bid >> 5;    // qt-major: balances causal triangle
    int b = bh >> 4, h = bh & 15;
    int q0 = qt * 64;
    int t = threadIdx.x, w = t >> 6, lane = t & 63, g = lane >> 4, c = lane & 15;
    const size_t bhQ = (size_t)(b * NH + h) * LEN;
    const size_t bhV = (size_t)(b * NH + h) * DHE;

    bf16x8 qa0, qa1;
    {
        const short* qp = Qb + (bhQ + q0 + w * 16 + c) * DHD;
        qa0 = *(const bf16x8*)(qp + g * 8);
        qa1 = *(const bf16x8*)(qp + 32 + g * 8);
    }
    float mrun[4] = {-1e30f, -1e30f, -1e30f, -1e30f};
    float lrun[4] = {0.f, 0.f, 0.f, 0.f};
    f32x4 o[5];
    for (int i = 0; i < 5; i++) o[i] = (f32x4){0.f, 0.f, 0.f, 0.f};

    for (int tt = 0; tt <= qt; tt++) {
        int kv0 = tt * 64;
        // stage K tile: 512 x 16B blocks
        #pragma unroll
        for (int rep = 0; rep < 2; rep++) {
            int bi = rep * 256 + t;
            int row = bi >> 3, blk = bi & 7;
            bf16x8 v = *(const bf16x8*)(Kb + (bhQ + kv0 + row) * DHD + blk * 8);
            *(bf16x8*)(Ks + row * 64 + ((blk ^ (row & 7)) * 8)) = v;
        }
        // stage V tile (transposed in global): 640 x 16B blocks
        #pragma unroll
        for (int rep = 0; rep < 3; rep++) {
            int bi = rep * 256 + t;
            if (bi < 640) {
                int d = bi >> 3, blk = bi & 7;
                bf16x8 v = *(const bf16x8*)(Vt + (bhV + d) * LEN + kv0 + blk * 8);
                *(bf16x8*)(Vs + d * 64 + ((blk ^ (d & 7)) * 8)) = v;
            }
        }
        __syncthreads();

        // S = Q K^T  (rows m = q-local, cols n = kv-local)
        f32x4 s[4];
        #pragma unroll
        for (int fn = 0; fn < 4; fn++) {
            int row = fn * 16 + c, sw = row & 7;
            bf16x8 kb0 = *(const bf16x8*)(Ks + row * 64 + ((g ^ sw) * 8));
            bf16x8 kb1 = *(const bf16x8*)(Ks + row * 64 + (((4 + g) ^ sw) * 8));
            f32x4 z = (f32x4){0.f, 0.f, 0.f, 0.f};
            z = mfma16(qa0, kb0, z);
            z = mfma16(qa1, kb1, z);
            s[fn] = z;
        }
        if (tt == qt) {   // diagonal tile: causal mask
            #pragma unroll
            for (int fn = 0; fn < 4; fn++) {
                int kv = kv0 + fn * 16 + c;
                #pragma unroll
                for (int i = 0; i < 4; i++) {
                    int q = q0 + w * 16 + g * 4 + i;
                    if (kv > q) s[fn][i] = -1e9f;
                }
            }
        }
        // online softmax (row = lane-group-local; reduce over 16 lanes)
        float scl[4];
        #pragma unroll
        for (int i = 0; i < 4; i++) {
            float mx = fmaxf(fmaxf(s[0][i], s[1][i]), fmaxf(s[2][i], s[3][i]));
            for (int off = 1; off < 16; off <<= 1) mx = fmaxf(mx, __shfl_xor(mx, off));
            float mnew = fmaxf(mrun[i], mx);
            scl[i] = __expf(mrun[i] - mnew);
            mrun[i] = mnew;
        }
        #pragma unroll
        for (int i = 0; i < 4; i++) {
            float ss = 0.f;
            #pragma unroll
            for (int fn = 0; fn < 4; fn++) {
                float p = __expf(s[fn][i] - mrun[i]);
                s[fn][i] = p;
                ss += p;
            }
            for (int off = 1; off < 16; off <<= 1) ss += __shfl_xor(ss, off);
            lrun[i] = lrun[i] * scl[i] + ss;
        }
        #pragma unroll
        for (int fd = 0; fd < 5; fd++)
            #pragma unroll
            for (int i = 0; i < 4; i++) o[fd][i] *= scl[i];

        // P -> LDS (C-layout to A-layout transpose), wave-private region
        short* pw = Ps[w];
        #pragma unroll
        for (int fn = 0; fn < 4; fn++)
            #pragma unroll
            for (int i = 0; i < 4; i++)
                pw[(g * 4 + i) * 72 + fn * 16 + c] = f2bf(s[fn][i]);
        bf16x8 pa0 = *(const bf16x8*)(pw + c * 72 + g * 8);
        bf16x8 pa1 = *(const bf16x8*)(pw + c * 72 + 32 + g * 8);

        // O += P V   (B-frags from transposed V tile)
        #pragma unroll
        for (int fd = 0; fd < 5; fd++) {
            int d = fd * 16 + c, sw = d & 7;
            bf16x8 vb0 = *(const bf16x8*)(Vs + d * 64 + ((g ^ sw) * 8));
            bf16x8 vb1 = *(const bf16x8*)(Vs + d * 64 + (((4 + g) ^ sw) * 8));
            o[fd] = mfma16(pa0, vb0, o[fd]);
            o[fd] = mfma16(pa1, vb1, o[fd]);
        }
        __syncthreads();
    }
    // epilogue: normalize and store Ctx
    #pragma unroll
    for (int i = 0; i < 4; i++) {
        float inv = 1.f / lrun[i];
        int q = q0 + w * 16 + g * 4 + i;
        size_t base = (bhQ + q) * DHE;
        #pragma unroll
        for (int fd = 0; fd < 5; fd++)
            Ctx[base + fd * 16 + c] = f2bf(o[fd][i] * inv);
    }
}

// ---------------------------------------------------------------------------
// Kernel 3: output projection  out[:, :1024] = Ctx @ Wo^T + bo   (fp32 out)
// ---------------------------------------------------------------------------
__global__ __launch_bounds__(256) void out_gemm(
    const short* __restrict__ Ctx, const short* __restrict__ Wo16,
    const float* __restrict__ bo, float* __restrict__ out)
{
    __shared__ short As[128 * 32];
    __shared__ short Bs[128 * 32];
    int bid = blockIdx.x;
    int nt = bid & 7, mt = bid >> 3;
    int t = threadIdx.x;
    int w = t >> 6, lane = t & 63, g = lane >> 4, c = lane & 15;
    int wr = w >> 1, wc = w & 1;

    f32x4 acc[4][4];
    for (int i = 0; i < 4; i++) for (int j = 0; j < 4; j++)
        acc[i][j] = (f32x4){0.f, 0.f, 0.f, 0.f};

    int sr = t >> 1, sh = t & 1;
    int tok = mt * 128 + sr;
    int b_ = tok >> 11, l = tok & 2047;
    const short* bSrc = Wo16 + (size_t)(nt * 128 + sr) * DIM + sh * 16;
    int swz = (sr >> 1) & 3;
    int wO0 = sr * 32 + (((sh * 2) ^ swz) * 8);
    int wO1 = sr * 32 + (((sh * 2 + 1) ^ swz) * 8);

    for (int k0 = 0; k0 < DIM; k0 += 32) {
        int hh = k0 >> 6, kin = (k0 & 63) + sh * 16;
        const short* aS = Ctx + ((size_t)(b_ * NH + hh) * LEN + l) * DHE + kin;
        bf16x8 av0 = *(const bf16x8*)(aS);
        bf16x8 av1 = *(const bf16x8*)(aS + 8);
        bf16x8 bv0 = *(const bf16x8*)(bSrc + k0);
        bf16x8 bv1 = *(const bf16x8*)(bSrc + k0 + 8);
        __syncthreads();
        *(bf16x8*)(As + wO0) = av0;
        *(bf16x8*)(As + wO1) = av1;
        *(bf16x8*)(Bs + wO0) = bv0;
        *(bf16x8*)(Bs + wO1) = bv1;
        __syncthreads();
        bf16x8 af[4], bfg[4];
        #pragma unroll
        for (int fm = 0; fm < 4; fm++) {
            int row = wr * 64 + fm * 16 + c;
            af[fm] = *(const bf16x8*)(As + row * 32 + ((g ^ ((row >> 1) & 3)) * 8));
        }
        #pragma unroll
        for (int fn = 0; fn < 4; fn++) {
            int row = wc * 64 + fn * 16 + c;
            bfg[fn] = *(const bf16x8*)(Bs + row * 32 + ((g ^ ((row >> 1) & 3)) * 8));
        }
        #pragma unroll
        for (int fm = 0; fm < 4; fm++)
            #pragma unroll
            for (int fn = 0; fn < 4; fn++)
                acc[fm][fn] = mfma16(af[fm], bfg[fn], acc[fm][fn]);
    }
    #pragma unroll
    for (int fn = 0; fn < 4; fn++) {
        int n = nt * 128 + wc * 64 + fn * 16 + c;
        float bval = bo[n];
        #pragma unroll
        for (int fm = 0; fm < 4; fm++) {
            int mbase = mt * 128 + wr * 64 + fm * 16 + g * 4;
            #pragma unroll
            for (int i = 0; i < 4; i++)
                out[(size_t)(mbase + i) * INW + n] = acc[fm][fn][i] + bval;
        }
    }
}

// ---------------------------------------------------------------------------
// Kernel 4: out[:, 1024:1040] = mean over heads of Ctx[..., 64:80]
// ---------------------------------------------------------------------------
__global__ __launch_bounds__(256) void encmean_kernel(
    const short* __restrict__ Ctx, float* __restrict__ out)
{
    int idx = blockIdx.x * 256 + threadIdx.x;   // 65536 = NTOK*POSD
    int tok = idx >> 4, p = idx & 15;
    int b = tok >> 11, l = tok & 2047;
    float s = 0.f;
    #pragma unroll
    for (int h = 0; h < NH; h++)
        s += bf2f(Ctx[((size_t)(b * NH + h) * LEN + l) * DHE + DHD + p]);
    out[(size_t)tok * INW + DIM + p] = s * (1.0f / NH);
}

// ---------------------------------------------------------------------------
extern "C" void kernel_launch(void* const* d_in, const int* in_sizes, int n_in,
                              void* d_out, int out_size, void* d_ws, size_t ws_size,
                              hipStream_t stream)
{
    const float* qin = (const float*)d_in[0];
    const float* kin = (const float*)d_in[1];
    const float* vin = (const float*)d_in[2];
    const float* Wq  = (const float*)d_in[3];
    const float* bq  = (const float*)d_in[4];
    const float* Wk  = (const float*)d_in[5];
    const float* bk  = (const float*)d_in[6];
    const float* Wv  = (const float*)d_in[7];
    const float* bv  = (const float*)d_in[8];
    const float* Wo  = (const float*)d_in[9];
    const float* bo  = (const float*)d_in[10];
    float* out = (float*)d_out;

    short* X16 = (short*)d_ws;                       // 3*NTOK*DIM
    short* W16 = X16 + (size_t)3 * NTOK * DIM;       // 4*DIM*DIM
    short* Qb  = W16 + (size_t)4 * DIM * DIM;        // NTOK*DIM
    short* Kb  = Qb  + (size_t)NTOK * DIM;           // NTOK*DIM
    short* Vt  = Kb  + (size_t)NTOK * DIM;           // BS*NH*DHE*LEN
    short* Ctx = Vt  + (size_t)BS * NH * DHE * LEN;  // BS*NH*LEN*DHE

    prep_kernel<<<16896, 256, 0, stream>>>(qin, kin, vin, Wq, Wk, Wv, Wo, X16, W16, Vt);
    qkv_gemm<<<768, 256, 0, stream>>>(X16, W16, bq, bk, bv, Qb, Kb, Vt);
    attn_kernel<<<1024, 256, 0, stream>>>(Qb, Kb, Vt, Ctx);
    out_gemm<<<256, 256, 0, stream>>>(Ctx, W16 + (size_t)3 * DIM * DIM, bo, out);
    encmean_kernel<<<256, 256, 0, stream>>>(Ctx, out);
}

// Round 2
// 152.713 us; speedup vs baseline: 1.2904x; 1.2904x over previous
//
#include <hip/hip_runtime.h>
#include <hip/hip_bf16.h>

#define BS   2
#define LEN  2048
#define DIM  1024
#define NH   16
#define DHD  64
#define POSD 16
#define DHE  80      // DHD + POSD (V extended with encoding)
#define NTOK 4096    // BS*LEN
#define INW  1040    // DIM + POSD input row width

typedef __attribute__((ext_vector_type(8))) short bf16x8;   // 8 bf16 = 4 VGPR
typedef __attribute__((ext_vector_type(4))) float f32x4;

__device__ __forceinline__ short f2bf(float f) {
    union { float f; unsigned u; } v; v.f = f;
    unsigned r = v.u + 0x7fffu + ((v.u >> 16) & 1u);
    return (short)(r >> 16);
}
__device__ __forceinline__ float bf2f(short s) {
    union { unsigned u; float f; } v; v.u = ((unsigned)(unsigned short)s) << 16;
    return v.f;
}
// pack two floats to two bf16 (round-half-up) in one u32
__device__ __forceinline__ unsigned packbf(float a, float b) {
    union { float f; unsigned u; } x, y; x.f = a; y.f = b;
    return ((x.u + 0x8000u) >> 16) | ((y.u + 0x8000u) & 0xFFFF0000u);
}
__device__ __forceinline__ f32x4 mfma16(bf16x8 a, bf16x8 b, f32x4 c) {
    return __builtin_amdgcn_mfma_f32_16x16x32_bf16(a, b, c, 0, 0, 0);
}

// ---------------------------------------------------------------------------
// Kernel 0: convert inputs/weights to bf16, and scatter encoding into Vt rows
// ---------------------------------------------------------------------------
__global__ __launch_bounds__(256) void prep_kernel(
    const float* __restrict__ qin, const float* __restrict__ kin, const float* __restrict__ vin,
    const float* __restrict__ Wq, const float* __restrict__ Wk,
    const float* __restrict__ Wv, const float* __restrict__ Wo,
    short* __restrict__ X16, short* __restrict__ W16, short* __restrict__ Vt)
{
    const int NA = 3 * NTOK * DIM / 4;
    const int NW = 4 * DIM * DIM / 4;
    int idx = blockIdx.x * 256 + threadIdx.x;
    if (idx < NA) {
        int per = NTOK * DIM / 4;
        int mi = idx / per, r = idx % per;
        int tok = r >> 8, c4 = r & 255;
        const float* src = (mi == 0 ? qin : (mi == 1 ? kin : vin));
        float4 v = *(const float4*)(src + (size_t)tok * INW + c4 * 4);
        short4 o;
        o.x = f2bf(v.x); o.y = f2bf(v.y); o.z = f2bf(v.z); o.w = f2bf(v.w);
        *(short4*)(X16 + (size_t)mi * NTOK * DIM + (size_t)tok * DIM + c4 * 4) = o;
        return;
    }
    idx -= NA;
    if (idx < NW) {
        int wi = idx >> 18, r = idx & 262143;
        const float* w = (wi == 0 ? Wq : (wi == 1 ? Wk : (wi == 2 ? Wv : Wo)));
        float4 v = *(const float4*)(w + (size_t)r * 4);
        short4 o;
        o.x = f2bf(v.x); o.y = f2bf(v.y); o.z = f2bf(v.z); o.w = f2bf(v.w);
        *(short4*)(W16 + (size_t)wi * DIM * DIM + (size_t)r * 4) = o;
        return;
    }
    idx -= NW;
    if (idx < BS * NH * POSD * (LEN / 8)) {
        int l8 = idx & 255;
        int p  = (idx >> 8) & 15;
        int h  = (idx >> 12) & 15;
        int b  = (idx >> 16);
        int l0 = l8 * 8;
        bf16x8 o;
        for (int i = 0; i < 8; i++)
            o[i] = f2bf(kin[(size_t)(b * LEN + l0 + i) * INW + DIM + p]);
        *(bf16x8*)(Vt + ((size_t)(b * NH + h) * DHE + DHD + p) * LEN + l0) = o;
    }
}

// ---------------------------------------------------------------------------
// Kernel 1: fused QKV projection GEMM.  Y = X @ W^T + b
// Q pre-scaled by (1/SCALE)*log2(e) so attention softmax runs in exp2 domain.
// ---------------------------------------------------------------------------
__global__ __launch_bounds__(256) void qkv_gemm(
    const short* __restrict__ X16, const short* __restrict__ W16,
    const float* __restrict__ bq, const float* __restrict__ bk, const float* __restrict__ bv,
    short* __restrict__ Qb, short* __restrict__ Kb, short* __restrict__ Vt)
{
    __shared__ short As[128 * 32];
    __shared__ short Bs[128 * 32];
    int bid = blockIdx.x;
    int nt = bid % 24, mt = bid / 24;
    int mat = nt >> 3, ntl = nt & 7;
    const short* A = X16 + (size_t)mat * NTOK * DIM;
    const short* W = W16 + (size_t)mat * DIM * DIM;

    int t = threadIdx.x;
    int w = t >> 6, lane = t & 63, g = lane >> 4, c = lane & 15;
    int wr = w >> 1, wc = w & 1;

    f32x4 acc[4][4];
    for (int i = 0; i < 4; i++) for (int j = 0; j < 4; j++)
        acc[i][j] = (f32x4){0.f, 0.f, 0.f, 0.f};

    int sr = t >> 1, sh = t & 1;
    const short* aSrc = A + (size_t)(mt * 128 + sr) * DIM + sh * 16;
    const short* bSrc = W + (size_t)(ntl * 128 + sr) * DIM + sh * 16;
    int swz = (sr >> 1) & 3;
    int wO0 = sr * 32 + (((sh * 2) ^ swz) * 8);
    int wO1 = sr * 32 + (((sh * 2 + 1) ^ swz) * 8);

    for (int k0 = 0; k0 < DIM; k0 += 32) {
        bf16x8 av0 = *(const bf16x8*)(aSrc + k0);
        bf16x8 av1 = *(const bf16x8*)(aSrc + k0 + 8);
        bf16x8 bv0 = *(const bf16x8*)(bSrc + k0);
        bf16x8 bv1 = *(const bf16x8*)(bSrc + k0 + 8);
        __syncthreads();
        *(bf16x8*)(As + wO0) = av0;
        *(bf16x8*)(As + wO1) = av1;
        *(bf16x8*)(Bs + wO0) = bv0;
        *(bf16x8*)(Bs + wO1) = bv1;
        __syncthreads();
        bf16x8 af[4], bfg[4];
        #pragma unroll
        for (int fm = 0; fm < 4; fm++) {
            int row = wr * 64 + fm * 16 + c;
            af[fm] = *(const bf16x8*)(As + row * 32 + ((g ^ ((row >> 1) & 3)) * 8));
        }
        #pragma unroll
        for (int fn = 0; fn < 4; fn++) {
            int row = wc * 64 + fn * 16 + c;
            bfg[fn] = *(const bf16x8*)(Bs + row * 32 + ((g ^ ((row >> 1) & 3)) * 8));
        }
        #pragma unroll
        for (int fm = 0; fm < 4; fm++)
            #pragma unroll
            for (int fn = 0; fn < 4; fn++)
                acc[fm][fn] = mfma16(af[fm], bfg[fn], acc[fm][fn]);
    }

    const float* bias = (mat == 0 ? bq : (mat == 1 ? bk : bv));
    float qs = (mat == 0) ? 0.18033688011112042f : 1.0f;  // (1/8)*log2(e) for Q
    #pragma unroll
    for (int fn = 0; fn < 4; fn++) {
        int n = ntl * 128 + wc * 64 + fn * 16 + c;
        float bval = bias[n];
        int h = n >> 6, dh = n & 63;
        #pragma unroll
        for (int fm = 0; fm < 4; fm++) {
            int mbase = mt * 128 + wr * 64 + fm * 16 + g * 4;
            #pragma unroll
            for (int i = 0; i < 4; i++) {
                int m = mbase + i;
                int b_ = m >> 11, l = m & 2047;
                short yb = f2bf((acc[fm][fn][i] + bval) * qs);
                if (mat == 2)
                    Vt[((size_t)(b_ * NH + h) * DHE + dh) * LEN + l] = yb;
                else if (mat == 0)
                    Qb[((size_t)(b_ * NH + h) * LEN + l) * DHD + dh] = yb;
                else
                    Kb[((size_t)(b_ * NH + h) * LEN + l) * DHD + dh] = yb;
            }
        }
    }
}

// ---------------------------------------------------------------------------
// Kernel 2: causal flash attention, swapped QK^T + reg-prefetch staging.
// 4 waves, q-tile 64 (16 q rows per wave), kv-tile 64, DHE=80.
// Swapped mfma(K,Q): lane (g,c) holds S[q=w*16+c][kv=fn*16+g*4+i] -> softmax
// row stats are 15 in-reg ops + 2 shuffles. Scores arrive log2-scaled.
// ---------------------------------------------------------------------------
__global__ __launch_bounds__(256) void attn_kernel(
    const short* __restrict__ Qb, const short* __restrict__ Kb,
    const short* __restrict__ Vt, short* __restrict__ Ctx)
{
    __shared__ __align__(16) short Ks[64 * 64];     // [kv][d], blk^(kv&7) swizzle
    __shared__ __align__(16) short Vs[DHE * 64];    // [d][kv], blk^(d&7) swizzle
    __shared__ __align__(16) short Ps[4][16 * 64];  // per-wave P[q][kv], blk^(q&7)

    int bid = blockIdx.x;
    int u = bid >> 5, bh = bid & 31;
    int qt = (u < 16) ? (2 * u) : (63 - 2 * u);   // balanced qt mix per CU
    int b = bh >> 4, h = bh & 15;
    int q0 = qt * 64;
    int t = threadIdx.x, w = t >> 6, lane = t & 63, g = lane >> 4, c = lane & 15;
    const size_t bhQ = (size_t)(b * NH + h) * LEN;
    const size_t bhV = (size_t)(b * NH + h) * DHE;

    // Q fragments (B-operand of swapped QK^T): Q[q=w*16+c][d=g*8+j]
    bf16x8 qa0, qa1;
    {
        const short* qp = Qb + (bhQ + q0 + w * 16 + c) * DHD;
        qa0 = *(const bf16x8*)(qp + g * 8);
        qa1 = *(const bf16x8*)(qp + 32 + g * 8);
    }

    // staging geometry: 16B chunk per thread per rep
    int rK = t >> 3, blkS = t & 7;
    int swzS = (blkS ^ (rK & 7)) * 8;              // (rK+32)&7 == rK&7
    short* kDst0 = Ks + rK * 64 + swzS;
    short* kDst1 = Ks + (rK + 32) * 64 + swzS;
    short* vDst0 = Vs + rK * 64 + swzS;
    short* vDst1 = Vs + (rK + 32) * 64 + swzS;
    short* vDst2 = Vs + (rK + 64) * 64 + swzS;
    const short* kS0 = Kb + (bhQ + rK) * DHD + blkS * 8;
    const short* kS1 = Kb + (bhQ + rK + 32) * DHD + blkS * 8;
    const short* vS0 = Vt + (bhV + rK) * LEN + blkS * 8;
    const short* vS1 = Vt + (bhV + rK + 32) * LEN + blkS * 8;
    const short* vS2 = Vt + (bhV + rK + 64) * LEN + blkS * 8;
    bool v2on = (t < 128);                          // V rows 64..79

    // prologue: stage kv-tile 0
    {
        bf16x8 a0 = *(const bf16x8*)kS0;
        bf16x8 a1 = *(const bf16x8*)kS1;
        bf16x8 x0 = *(const bf16x8*)vS0;
        bf16x8 x1 = *(const bf16x8*)vS1;
        bf16x8 x2;
        if (v2on) x2 = *(const bf16x8*)vS2;
        *(bf16x8*)kDst0 = a0;
        *(bf16x8*)kDst1 = a1;
        *(bf16x8*)vDst0 = x0;
        *(bf16x8*)vDst1 = x1;
        if (v2on) *(bf16x8*)vDst2 = x2;
    }
    __syncthreads();

    float mrun = -1e30f, lrun = 0.f;
    f32x4 o[5];
    #pragma unroll
    for (int i = 0; i < 5; i++) o[i] = (f32x4){0.f, 0.f, 0.f, 0.f};

    for (int tt = 0; tt <= qt; tt++) {
        // T14: issue next tile's global loads now; latency hides under compute
        bf16x8 kr0, kr1, vr0, vr1, vr2;
        bool pref = (tt < qt);
        if (pref) {
            int kvn = (tt + 1) * 64;
            kr0 = *(const bf16x8*)(kS0 + (size_t)kvn * DHD);
            kr1 = *(const bf16x8*)(kS1 + (size_t)kvn * DHD);
            vr0 = *(const bf16x8*)(vS0 + kvn);
            vr1 = *(const bf16x8*)(vS1 + kvn);
            if (v2on) vr2 = *(const bf16x8*)(vS2 + kvn);
        }

        // S^T = K·Q^T : st[fn][i] = S[q=w*16+c][kv=fn*16+g*4+i] (log2 domain)
        f32x4 st[4];
        __builtin_amdgcn_s_setprio(1);
        #pragma unroll
        for (int fn = 0; fn < 4; fn++) {
            int row = fn * 16 + c, sw = row & 7;
            bf16x8 ka = *(const bf16x8*)(Ks + row * 64 + ((g ^ sw) * 8));
            bf16x8 kb2 = *(const bf16x8*)(Ks + row * 64 + (((4 + g) ^ sw) * 8));
            f32x4 z = (f32x4){0.f, 0.f, 0.f, 0.f};
            z = mfma16(ka, qa0, z);
            z = mfma16(kb2, qa1, z);
            st[fn] = z;
        }
        __builtin_amdgcn_s_setprio(0);

        if (tt == qt) {   // causal mask on diagonal tile
            #pragma unroll
            for (int fn = 0; fn < 4; fn++)
                #pragma unroll
                for (int i = 0; i < 4; i++)
                    if (fn * 16 + g * 4 + i > w * 16 + c) st[fn][i] = -1e9f;
        }

        // online softmax: per-thread 16 values, then reduce across 4 g-lanes
        float mx = st[0][0];
        #pragma unroll
        for (int fn = 0; fn < 4; fn++)
            #pragma unroll
            for (int i = 0; i < 4; i++)
                mx = fmaxf(mx, st[fn][i]);
        mx = fmaxf(mx, __shfl_xor(mx, 16));
        mx = fmaxf(mx, __shfl_xor(mx, 32));
        float mnew = fmaxf(mrun, mx);
        float scl = __builtin_amdgcn_exp2f(mrun - mnew);
        mrun = mnew;
        float ps = 0.f;
        #pragma unroll
        for (int fn = 0; fn < 4; fn++)
            #pragma unroll
            for (int i = 0; i < 4; i++) {
                float p = __builtin_amdgcn_exp2f(st[fn][i] - mnew);
                st[fn][i] = p;
                ps += p;
            }
        ps += __shfl_xor(ps, 16);
        ps += __shfl_xor(ps, 32);
        lrun = lrun * scl + ps;

        // P -> LDS (wave-private): 4x ds_write_b64, then 2x ds_read_b128
        short* pw = Ps[w];
        #pragma unroll
        for (int fn = 0; fn < 4; fn++) {
            uint2 pu;
            pu.x = packbf(st[fn][0], st[fn][1]);
            pu.y = packbf(st[fn][2], st[fn][3]);
            *(uint2*)(pw + c * 64 + ((((fn << 1) | (g >> 1)) ^ (c & 7)) << 3) + ((g & 1) << 2)) = pu;
        }
        bf16x8 pa0 = *(const bf16x8*)(pw + c * 64 + ((g ^ (c & 7)) * 8));
        bf16x8 pa1 = *(const bf16x8*)(pw + c * 64 + (((4 + g) ^ (c & 7)) * 8));

        // rescale O (output rows are q = g*4+i; fetch their scl via shuffle)
        float s0 = __shfl(scl, g * 4 + 0);
        float s1 = __shfl(scl, g * 4 + 1);
        float s2 = __shfl(scl, g * 4 + 2);
        float s3 = __shfl(scl, g * 4 + 3);
        #pragma unroll
        for (int fd = 0; fd < 5; fd++) {
            o[fd][0] *= s0; o[fd][1] *= s1; o[fd][2] *= s2; o[fd][3] *= s3;
        }

        // O += P·V
        __builtin_amdgcn_s_setprio(1);
        #pragma unroll
        for (int fd = 0; fd < 5; fd++) {
            int d = fd * 16 + c, sw = d & 7;
            bf16x8 vb0 = *(const bf16x8*)(Vs + d * 64 + ((g ^ sw) * 8));
            bf16x8 vb1 = *(const bf16x8*)(Vs + d * 64 + (((4 + g) ^ sw) * 8));
            o[fd] = mfma16(pa0, vb0, o[fd]);
            o[fd] = mfma16(pa1, vb1, o[fd]);
        }
        __builtin_amdgcn_s_setprio(0);

        __syncthreads();            // all waves done reading K/V tile tt
        if (pref) {
            *(bf16x8*)kDst0 = kr0;
            *(bf16x8*)kDst1 = kr1;
            *(bf16x8*)vDst0 = vr0;
            *(bf16x8*)vDst1 = vr1;
            if (v2on) *(bf16x8*)vDst2 = vr2;
        }
        __syncthreads();            // tile tt+1 published
    }

    // epilogue: normalize and store (output rows q = w*16 + g*4 + i)
    float l0 = __shfl(lrun, g * 4 + 0);
    float l1 = __shfl(lrun, g * 4 + 1);
    float l2 = __shfl(lrun, g * 4 + 2);
    float l3 = __shfl(lrun, g * 4 + 3);
    float inv[4] = {1.f / l0, 1.f / l1, 1.f / l2, 1.f / l3};
    #pragma unroll
    for (int i = 0; i < 4; i++) {
        int q = q0 + w * 16 + g * 4 + i;
        size_t base = (bhQ + q) * DHE;
        #pragma unroll
        for (int fd = 0; fd < 5; fd++)
            Ctx[base + fd * 16 + c] = f2bf(o[fd][i] * inv[i]);
    }
}

// ---------------------------------------------------------------------------
// Kernel 3: output projection  out[:, :1024] = Ctx @ Wo^T + bo   (fp32 out)
// ---------------------------------------------------------------------------
__global__ __launch_bounds__(256) void out_gemm(
    const short* __restrict__ Ctx, const short* __restrict__ Wo16,
    const float* __restrict__ bo, float* __restrict__ out)
{
    __shared__ short As[128 * 32];
    __shared__ short Bs[128 * 32];
    int bid = blockIdx.x;
    int nt = bid & 7, mt = bid >> 3;
    int t = threadIdx.x;
    int w = t >> 6, lane = t & 63, g = lane >> 4, c = lane & 15;
    int wr = w >> 1, wc = w & 1;

    f32x4 acc[4][4];
    for (int i = 0; i < 4; i++) for (int j = 0; j < 4; j++)
        acc[i][j] = (f32x4){0.f, 0.f, 0.f, 0.f};

    int sr = t >> 1, sh = t & 1;
    int tok = mt * 128 + sr;
    int b_ = tok >> 11, l = tok & 2047;
    const short* bSrc = Wo16 + (size_t)(nt * 128 + sr) * DIM + sh * 16;
    int swz = (sr >> 1) & 3;
    int wO0 = sr * 32 + (((sh * 2) ^ swz) * 8);
    int wO1 = sr * 32 + (((sh * 2 + 1) ^ swz) * 8);

    for (int k0 = 0; k0 < DIM; k0 += 32) {
        int hh = k0 >> 6, kin = (k0 & 63) + sh * 16;
        const short* aS = Ctx + ((size_t)(b_ * NH + hh) * LEN + l) * DHE + kin;
        bf16x8 av0 = *(const bf16x8*)(aS);
        bf16x8 av1 = *(const bf16x8*)(aS + 8);
        bf16x8 bv0 = *(const bf16x8*)(bSrc + k0);
        bf16x8 bv1 = *(const bf16x8*)(bSrc + k0 + 8);
        __syncthreads();
        *(bf16x8*)(As + wO0) = av0;
        *(bf16x8*)(As + wO1) = av1;
        *(bf16x8*)(Bs + wO0) = bv0;
        *(bf16x8*)(Bs + wO1) = bv1;
        __syncthreads();
        bf16x8 af[4], bfg[4];
        #pragma unroll
        for (int fm = 0; fm < 4; fm++) {
            int row = wr * 64 + fm * 16 + c;
            af[fm] = *(const bf16x8*)(As + row * 32 + ((g ^ ((row >> 1) & 3)) * 8));
        }
        #pragma unroll
        for (int fn = 0; fn < 4; fn++) {
            int row = wc * 64 + fn * 16 + c;
            bfg[fn] = *(const bf16x8*)(Bs + row * 32 + ((g ^ ((row >> 1) & 3)) * 8));
        }
        #pragma unroll
        for (int fm = 0; fm < 4; fm++)
            #pragma unroll
            for (int fn = 0; fn < 4; fn++)
                acc[fm][fn] = mfma16(af[fm], bfg[fn], acc[fm][fn]);
    }
    #pragma unroll
    for (int fn = 0; fn < 4; fn++) {
        int n = nt * 128 + wc * 64 + fn * 16 + c;
        float bval = bo[n];
        #pragma unroll
        for (int fm = 0; fm < 4; fm++) {
            int mbase = mt * 128 + wr * 64 + fm * 16 + g * 4;
            #pragma unroll
            for (int i = 0; i < 4; i++)
                out[(size_t)(mbase + i) * INW + n] = acc[fm][fn][i] + bval;
        }
    }
}

// ---------------------------------------------------------------------------
// Kernel 4: out[:, 1024:1040] = mean over heads of Ctx[..., 64:80]
// ---------------------------------------------------------------------------
__global__ __launch_bounds__(256) void encmean_kernel(
    const short* __restrict__ Ctx, float* __restrict__ out)
{
    int idx = blockIdx.x * 256 + threadIdx.x;   // 65536 = NTOK*POSD
    int tok = idx >> 4, p = idx & 15;
    int b = tok >> 11, l = tok & 2047;
    float s = 0.f;
    #pragma unroll
    for (int h = 0; h < NH; h++)
        s += bf2f(Ctx[((size_t)(b * NH + h) * LEN + l) * DHE + DHD + p]);
    out[(size_t)tok * INW + DIM + p] = s * (1.0f / NH);
}

// ---------------------------------------------------------------------------
extern "C" void kernel_launch(void* const* d_in, const int* in_sizes, int n_in,
                              void* d_out, int out_size, void* d_ws, size_t ws_size,
                              hipStream_t stream)
{
    const float* qin = (const float*)d_in[0];
    const float* kin = (const float*)d_in[1];
    const float* vin = (const float*)d_in[2];
    const float* Wq  = (const float*)d_in[3];
    const float* bq  = (const float*)d_in[4];
    const float* Wk  = (const float*)d_in[5];
    const float* bk  = (const float*)d_in[6];
    const float* Wv  = (const float*)d_in[7];
    const float* bv  = (const float*)d_in[8];
    const float* Wo  = (const float*)d_in[9];
    const float* bo  = (const float*)d_in[10];
    float* out = (float*)d_out;

    short* X16 = (short*)d_ws;                       // 3*NTOK*DIM
    short* W16 = X16 + (size_t)3 * NTOK * DIM;       // 4*DIM*DIM
    short* Qb  = W16 + (size_t)4 * DIM * DIM;        // NTOK*DIM
    short* Kb  = Qb  + (size_t)NTOK * DIM;           // NTOK*DIM
    short* Vt  = Kb  + (size_t)NTOK * DIM;           // BS*NH*DHE*LEN
    short* Ctx = Vt  + (size_t)BS * NH * DHE * LEN;  // BS*NH*LEN*DHE

    prep_kernel<<<16896, 256, 0, stream>>>(qin, kin, vin, Wq, Wk, Wv, Wo, X16, W16, Vt);
    qkv_gemm<<<768, 256, 0, stream>>>(X16, W16, bq, bk, bv, Qb, Kb, Vt);
    attn_kernel<<<1024, 256, 0, stream>>>(Qb, Kb, Vt, Ctx);
    out_gemm<<<256, 256, 0, stream>>>(Ctx, W16 + (size_t)3 * DIM * DIM, bo, out);
    encmean_kernel<<<256, 256, 0, stream>>>(Ctx, out);
}

// Round 3
// 152.381 us; speedup vs baseline: 1.2933x; 1.0022x over previous
//
#include <hip/hip_runtime.h>
#include <hip/hip_bf16.h>

#define BS   2
#define LEN  2048
#define DIM  1024
#define NH   16
#define DHD  64
#define POSD 16
#define DHE  80      // DHD + POSD (V extended with encoding)
#define NTOK 4096    // BS*LEN
#define INW  1040    // DIM + POSD input row width

typedef __attribute__((ext_vector_type(8))) short bf16x8;   // 8 bf16 = 4 VGPR
typedef __attribute__((ext_vector_type(4))) float f32x4;

__device__ __forceinline__ short f2bf(float f) {
    union { float f; unsigned u; } v; v.f = f;
    unsigned r = v.u + 0x7fffu + ((v.u >> 16) & 1u);
    return (short)(r >> 16);
}
__device__ __forceinline__ float bf2f(short s) {
    union { unsigned u; float f; } v; v.u = ((unsigned)(unsigned short)s) << 16;
    return v.f;
}
__device__ __forceinline__ unsigned packbf(float a, float b) {
    union { float f; unsigned u; } x, y; x.f = a; y.f = b;
    return ((x.u + 0x8000u) >> 16) | ((y.u + 0x8000u) & 0xFFFF0000u);
}
__device__ __forceinline__ f32x4 mfma16(bf16x8 a, bf16x8 b, f32x4 c) {
    return __builtin_amdgcn_mfma_f32_16x16x32_bf16(a, b, c, 0, 0, 0);
}
// async global->LDS, 16B per lane; lds dest must be wave-uniform base (HW adds lane*16)
__device__ __forceinline__ void gld16(const short* g, short* l) {
    __builtin_amdgcn_global_load_lds(
        (const __attribute__((address_space(1))) unsigned int*)g,
        (__attribute__((address_space(3))) unsigned int*)l,
        16, 0, 0);
}

// ---------------------------------------------------------------------------
// Kernel 0: convert inputs/weights to bf16, and scatter encoding into Vt rows
// ---------------------------------------------------------------------------
__global__ __launch_bounds__(256) void prep_kernel(
    const float* __restrict__ qin, const float* __restrict__ kin, const float* __restrict__ vin,
    const float* __restrict__ Wq, const float* __restrict__ Wk,
    const float* __restrict__ Wv, const float* __restrict__ Wo,
    short* __restrict__ X16, short* __restrict__ W16, short* __restrict__ Vt)
{
    const int NA = 3 * NTOK * DIM / 4;
    const int NW = 4 * DIM * DIM / 4;
    int idx = blockIdx.x * 256 + threadIdx.x;
    if (idx < NA) {
        int per = NTOK * DIM / 4;
        int mi = idx / per, r = idx % per;
        int tok = r >> 8, c4 = r & 255;
        const float* src = (mi == 0 ? qin : (mi == 1 ? kin : vin));
        float4 v = *(const float4*)(src + (size_t)tok * INW + c4 * 4);
        short4 o;
        o.x = f2bf(v.x); o.y = f2bf(v.y); o.z = f2bf(v.z); o.w = f2bf(v.w);
        *(short4*)(X16 + (size_t)mi * NTOK * DIM + (size_t)tok * DIM + c4 * 4) = o;
        return;
    }
    idx -= NA;
    if (idx < NW) {
        int wi = idx >> 18, r = idx & 262143;
        const float* w = (wi == 0 ? Wq : (wi == 1 ? Wk : (wi == 2 ? Wv : Wo)));
        float4 v = *(const float4*)(w + (size_t)r * 4);
        short4 o;
        o.x = f2bf(v.x); o.y = f2bf(v.y); o.z = f2bf(v.z); o.w = f2bf(v.w);
        *(short4*)(W16 + (size_t)wi * DIM * DIM + (size_t)r * 4) = o;
        return;
    }
    idx -= NW;
    if (idx < BS * NH * POSD * (LEN / 8)) {
        int l8 = idx & 255;
        int p  = (idx >> 8) & 15;
        int h  = (idx >> 12) & 15;
        int b  = (idx >> 16);
        int l0 = l8 * 8;
        bf16x8 o;
        for (int i = 0; i < 8; i++)
            o[i] = f2bf(kin[(size_t)(b * LEN + l0 + i) * INW + DIM + p]);
        *(bf16x8*)(Vt + ((size_t)(b * NH + h) * DHE + DHD + p) * LEN + l0) = o;
    }
}

// ---------------------------------------------------------------------------
// Kernel 1: fused QKV projection GEMM (m97 structure).
// 128x128 tile, BK=64, global_load_lds width=16, linear LDS, 4 waves (2x2).
// V output transposed via padded-LDS tile -> vectorized 16B stores.
// Q pre-scaled by (1/SCALE)*log2(e) so attention softmax runs in exp2 domain.
// ---------------------------------------------------------------------------
__global__ __launch_bounds__(256) void qkv_gemm(
    const short* __restrict__ X16, const short* __restrict__ W16,
    const float* __restrict__ bq, const float* __restrict__ bk, const float* __restrict__ bv,
    short* __restrict__ Qb, short* __restrict__ Kb, short* __restrict__ Vt)
{
    __shared__ __align__(16) short smem[17408];   // As(8192) + Bs(8192); reused 128x136 for V transpose
    short* As = smem;
    short* Bs = smem + 8192;

    int sw = (blockIdx.x & 7) * 96 + (blockIdx.x >> 3);   // XCD-bijective swizzle (768%8==0)
    int nt = sw % 24, mt = sw / 24;
    int mat = nt >> 3, ntl = nt & 7;
    const short* A = X16 + (size_t)mat * NTOK * DIM;
    const short* W = W16 + (size_t)mat * DIM * DIM;

    int t = threadIdx.x;
    int w = t >> 6, lane = t & 63, g = lane >> 4, c = lane & 15;
    int wr = w >> 1, wc = w & 1;

    f32x4 acc[4][4];
    #pragma unroll
    for (int i = 0; i < 4; i++)
        #pragma unroll
        for (int j = 0; j < 4; j++)
            acc[i][j] = (f32x4){0.f, 0.f, 0.f, 0.f};

    // staging: thread t handles row (t>>3), 16B block (t&7) of a 32-row chunk
    const short* aSrc = A + (size_t)(mt * 128 + (t >> 3)) * DIM + (t & 7) * 8;
    const short* bSrc = W + (size_t)(ntl * 128 + (t >> 3)) * DIM + (t & 7) * 8;
    short* aDst = As + w * 512;    // + j*2048 per 32-row chunk; HW adds lane*16B
    short* bDst = Bs + w * 512;

    for (int k0 = 0; k0 < DIM; k0 += 64) {
        __syncthreads();                       // previous iter's LDS reads done
        #pragma unroll
        for (int j = 0; j < 4; j++) {
            gld16(aSrc + k0 + j * 32 * DIM, aDst + j * 2048);
            gld16(bSrc + k0 + j * 32 * DIM, bDst + j * 2048);
        }
        __syncthreads();                       // drains vmcnt(0); tiles published
        #pragma unroll
        for (int ks = 0; ks < 2; ks++) {
            bf16x8 af[4], bfr[4];
            #pragma unroll
            for (int fm = 0; fm < 4; fm++)
                af[fm] = *(const bf16x8*)(As + (wr * 64 + fm * 16 + c) * 64 + ks * 32 + g * 8);
            #pragma unroll
            for (int fn = 0; fn < 4; fn++)
                bfr[fn] = *(const bf16x8*)(Bs + (wc * 64 + fn * 16 + c) * 64 + ks * 32 + g * 8);
            #pragma unroll
            for (int fm = 0; fm < 4; fm++)
                #pragma unroll
                for (int fn = 0; fn < 4; fn++)
                    acc[fm][fn] = mfma16(af[fm], bfr[fn], acc[fm][fn]);
        }
    }

    const float* bias = (mat == 0 ? bq : (mat == 1 ? bk : bv));
    if (mat == 2) {
        // V: transpose 128x128 tile through LDS (stride 136), then 16B stores
        __syncthreads();
        #pragma unroll
        for (int fn = 0; fn < 4; fn++) {
            int nl = wc * 64 + fn * 16 + c;
            float bval = bias[ntl * 128 + nl];
            #pragma unroll
            for (int fm = 0; fm < 4; fm++) {
                int m0 = wr * 64 + fm * 16 + g * 4;
                short4 pk;
                pk.x = f2bf(acc[fm][fn][0] + bval);
                pk.y = f2bf(acc[fm][fn][1] + bval);
                pk.z = f2bf(acc[fm][fn][2] + bval);
                pk.w = f2bf(acc[fm][fn][3] + bval);
                *(short4*)(smem + nl * 136 + m0) = pk;
            }
        }
        __syncthreads();
        int b_ = (mt * 128) >> 11;
        int l0 = (mt * 128) & 2047;
        #pragma unroll
        for (int rep = 0; rep < 8; rep++) {
            int idx = rep * 256 + t;
            int row = idx >> 4, ch = idx & 15;
            bf16x8 v = *(const bf16x8*)(smem + row * 136 + ch * 8);
            int ng = ntl * 128 + row, h = ng >> 6, dh = ng & 63;
            *(bf16x8*)(Vt + ((size_t)(b_ * NH + h) * DHE + dh) * LEN + l0 + ch * 8) = v;
        }
    } else {
        float qs = (mat == 0) ? 0.18033688011112042f : 1.0f;  // (1/8)*log2(e) for Q
        short* dst = (mat == 0) ? Qb : Kb;
        #pragma unroll
        for (int fn = 0; fn < 4; fn++) {
            int n = ntl * 128 + wc * 64 + fn * 16 + c;
            float bval = bias[n];
            int h = n >> 6, dh = n & 63;
            #pragma unroll
            for (int fm = 0; fm < 4; fm++) {
                int mbase = mt * 128 + wr * 64 + fm * 16 + g * 4;
                #pragma unroll
                for (int i = 0; i < 4; i++) {
                    int m = mbase + i;
                    int b_ = m >> 11, l = m & 2047;
                    dst[((size_t)(b_ * NH + h) * LEN + l) * DHD + dh] =
                        f2bf((acc[fm][fn][i] + bval) * qs);
                }
            }
        }
    }
}

// ---------------------------------------------------------------------------
// Kernel 2: causal flash attention, swapped QK^T + reg-prefetch staging.
// 4 waves, q-tile 64 (16 q rows per wave), kv-tile 64, DHE=80.
// ---------------------------------------------------------------------------
__global__ __launch_bounds__(256) void attn_kernel(
    const short* __restrict__ Qb, const short* __restrict__ Kb,
    const short* __restrict__ Vt, short* __restrict__ Ctx)
{
    __shared__ __align__(16) short Ks[64 * 64];     // [kv][d], blk^(kv&7) swizzle
    __shared__ __align__(16) short Vs[DHE * 64];    // [d][kv], blk^(d&7) swizzle
    __shared__ __align__(16) short Ps[4][16 * 64];  // per-wave P[q][kv], blk^(q&7)

    int bid = blockIdx.x;
    int u = bid >> 5, bh = bid & 31;
    int qt = (u < 16) ? (2 * u) : (63 - 2 * u);   // balanced qt mix per CU
    int b = bh >> 4, h = bh & 15;
    int q0 = qt * 64;
    int t = threadIdx.x, w = t >> 6, lane = t & 63, g = lane >> 4, c = lane & 15;
    const size_t bhQ = (size_t)(b * NH + h) * LEN;
    const size_t bhV = (size_t)(b * NH + h) * DHE;

    bf16x8 qa0, qa1;
    {
        const short* qp = Qb + (bhQ + q0 + w * 16 + c) * DHD;
        qa0 = *(const bf16x8*)(qp + g * 8);
        qa1 = *(const bf16x8*)(qp + 32 + g * 8);
    }

    int rK = t >> 3, blkS = t & 7;
    int swzS = (blkS ^ (rK & 7)) * 8;
    short* kDst0 = Ks + rK * 64 + swzS;
    short* kDst1 = Ks + (rK + 32) * 64 + swzS;
    short* vDst0 = Vs + rK * 64 + swzS;
    short* vDst1 = Vs + (rK + 32) * 64 + swzS;
    short* vDst2 = Vs + (rK + 64) * 64 + swzS;
    const short* kS0 = Kb + (bhQ + rK) * DHD + blkS * 8;
    const short* kS1 = Kb + (bhQ + rK + 32) * DHD + blkS * 8;
    const short* vS0 = Vt + (bhV + rK) * LEN + blkS * 8;
    const short* vS1 = Vt + (bhV + rK + 32) * LEN + blkS * 8;
    const short* vS2 = Vt + (bhV + rK + 64) * LEN + blkS * 8;
    bool v2on = (t < 128);

    {
        bf16x8 a0 = *(const bf16x8*)kS0;
        bf16x8 a1 = *(const bf16x8*)kS1;
        bf16x8 x0 = *(const bf16x8*)vS0;
        bf16x8 x1 = *(const bf16x8*)vS1;
        bf16x8 x2;
        if (v2on) x2 = *(const bf16x8*)vS2;
        *(bf16x8*)kDst0 = a0;
        *(bf16x8*)kDst1 = a1;
        *(bf16x8*)vDst0 = x0;
        *(bf16x8*)vDst1 = x1;
        if (v2on) *(bf16x8*)vDst2 = x2;
    }
    __syncthreads();

    float mrun = -1e30f, lrun = 0.f;
    f32x4 o[5];
    #pragma unroll
    for (int i = 0; i < 5; i++) o[i] = (f32x4){0.f, 0.f, 0.f, 0.f};

    for (int tt = 0; tt <= qt; tt++) {
        bf16x8 kr0, kr1, vr0, vr1, vr2;
        bool pref = (tt < qt);
        if (pref) {
            int kvn = (tt + 1) * 64;
            kr0 = *(const bf16x8*)(kS0 + (size_t)kvn * DHD);
            kr1 = *(const bf16x8*)(kS1 + (size_t)kvn * DHD);
            vr0 = *(const bf16x8*)(vS0 + kvn);
            vr1 = *(const bf16x8*)(vS1 + kvn);
            if (v2on) vr2 = *(const bf16x8*)(vS2 + kvn);
        }

        f32x4 st[4];
        __builtin_amdgcn_s_setprio(1);
        #pragma unroll
        for (int fn = 0; fn < 4; fn++) {
            int row = fn * 16 + c, sw2 = row & 7;
            bf16x8 ka = *(const bf16x8*)(Ks + row * 64 + ((g ^ sw2) * 8));
            bf16x8 kb2 = *(const bf16x8*)(Ks + row * 64 + (((4 + g) ^ sw2) * 8));
            f32x4 z = (f32x4){0.f, 0.f, 0.f, 0.f};
            z = mfma16(ka, qa0, z);
            z = mfma16(kb2, qa1, z);
            st[fn] = z;
        }
        __builtin_amdgcn_s_setprio(0);

        if (tt == qt) {
            #pragma unroll
            for (int fn = 0; fn < 4; fn++)
                #pragma unroll
                for (int i = 0; i < 4; i++)
                    if (fn * 16 + g * 4 + i > w * 16 + c) st[fn][i] = -1e9f;
        }

        float mx = st[0][0];
        #pragma unroll
        for (int fn = 0; fn < 4; fn++)
            #pragma unroll
            for (int i = 0; i < 4; i++)
                mx = fmaxf(mx, st[fn][i]);
        mx = fmaxf(mx, __shfl_xor(mx, 16));
        mx = fmaxf(mx, __shfl_xor(mx, 32));
        float mnew = fmaxf(mrun, mx);
        float scl = __builtin_amdgcn_exp2f(mrun - mnew);
        mrun = mnew;
        float ps = 0.f;
        #pragma unroll
        for (int fn = 0; fn < 4; fn++)
            #pragma unroll
            for (int i = 0; i < 4; i++) {
                float p = __builtin_amdgcn_exp2f(st[fn][i] - mnew);
                st[fn][i] = p;
                ps += p;
            }
        ps += __shfl_xor(ps, 16);
        ps += __shfl_xor(ps, 32);
        lrun = lrun * scl + ps;

        short* pw = Ps[w];
        #pragma unroll
        for (int fn = 0; fn < 4; fn++) {
            uint2 pu;
            pu.x = packbf(st[fn][0], st[fn][1]);
            pu.y = packbf(st[fn][2], st[fn][3]);
            *(uint2*)(pw + c * 64 + ((((fn << 1) | (g >> 1)) ^ (c & 7)) << 3) + ((g & 1) << 2)) = pu;
        }
        bf16x8 pa0 = *(const bf16x8*)(pw + c * 64 + ((g ^ (c & 7)) * 8));
        bf16x8 pa1 = *(const bf16x8*)(pw + c * 64 + (((4 + g) ^ (c & 7)) * 8));

        float s0 = __shfl(scl, g * 4 + 0);
        float s1 = __shfl(scl, g * 4 + 1);
        float s2 = __shfl(scl, g * 4 + 2);
        float s3 = __shfl(scl, g * 4 + 3);
        #pragma unroll
        for (int fd = 0; fd < 5; fd++) {
            o[fd][0] *= s0; o[fd][1] *= s1; o[fd][2] *= s2; o[fd][3] *= s3;
        }

        __builtin_amdgcn_s_setprio(1);
        #pragma unroll
        for (int fd = 0; fd < 5; fd++) {
            int d = fd * 16 + c, sw2 = d & 7;
            bf16x8 vb0 = *(const bf16x8*)(Vs + d * 64 + ((g ^ sw2) * 8));
            bf16x8 vb1 = *(const bf16x8*)(Vs + d * 64 + (((4 + g) ^ sw2) * 8));
            o[fd] = mfma16(pa0, vb0, o[fd]);
            o[fd] = mfma16(pa1, vb1, o[fd]);
        }
        __builtin_amdgcn_s_setprio(0);

        __syncthreads();
        if (pref) {
            *(bf16x8*)kDst0 = kr0;
            *(bf16x8*)kDst1 = kr1;
            *(bf16x8*)vDst0 = vr0;
            *(bf16x8*)vDst1 = vr1;
            if (v2on) *(bf16x8*)vDst2 = vr2;
        }
        __syncthreads();
    }

    float l0 = __shfl(lrun, g * 4 + 0);
    float l1 = __shfl(lrun, g * 4 + 1);
    float l2 = __shfl(lrun, g * 4 + 2);
    float l3 = __shfl(lrun, g * 4 + 3);
    float inv[4] = {1.f / l0, 1.f / l1, 1.f / l2, 1.f / l3};
    #pragma unroll
    for (int i = 0; i < 4; i++) {
        int q = q0 + w * 16 + g * 4 + i;
        size_t base = (bhQ + q) * DHE;
        #pragma unroll
        for (int fd = 0; fd < 5; fd++)
            Ctx[base + fd * 16 + c] = f2bf(o[fd][i] * inv[i]);
    }
}

// ---------------------------------------------------------------------------
// Kernel 3: output projection (m97 structure), out[:, :1024] = Ctx @ Wo^T + bo
// ---------------------------------------------------------------------------
__global__ __launch_bounds__(256) void out_gemm(
    const short* __restrict__ Ctx, const short* __restrict__ Wo16,
    const float* __restrict__ bo, float* __restrict__ out)
{
    __shared__ __align__(16) short As[128 * 64];
    __shared__ __align__(16) short Bs[128 * 64];

    int sw = (blockIdx.x & 7) * 32 + (blockIdx.x >> 3);   // XCD swizzle (256%8==0)
    int nt = sw & 7, mt = sw >> 3;
    int t = threadIdx.x;
    int w = t >> 6, lane = t & 63, g = lane >> 4, c = lane & 15;
    int wr = w >> 1, wc = w & 1;

    f32x4 acc[4][4];
    #pragma unroll
    for (int i = 0; i < 4; i++)
        #pragma unroll
        for (int j = 0; j < 4; j++)
            acc[i][j] = (f32x4){0.f, 0.f, 0.f, 0.f};

    // A rows are tokens; k dims hop heads every 64 (head h = k0>>6 per K-step)
    int tokS = mt * 128 + (t >> 3);
    int bS = tokS >> 11, lS = tokS & 2047;
    const short* aBase = Ctx + ((size_t)bS * NH * LEN + lS) * DHE + (t & 7) * 8;
    const short* bSrc = Wo16 + (size_t)(nt * 128 + (t >> 3)) * DIM + (t & 7) * 8;
    short* aDst = As + w * 512;
    short* bDst = Bs + w * 512;

    for (int k0 = 0; k0 < DIM; k0 += 64) {
        const short* aS = aBase + (size_t)(k0 >> 6) * LEN * DHE;
        __syncthreads();
        #pragma unroll
        for (int j = 0; j < 4; j++) {
            gld16(aS + (size_t)j * 32 * DHE, aDst + j * 2048);
            gld16(bSrc + k0 + j * 32 * DIM, bDst + j * 2048);
        }
        __syncthreads();
        #pragma unroll
        for (int ks = 0; ks < 2; ks++) {
            bf16x8 af[4], bfr[4];
            #pragma unroll
            for (int fm = 0; fm < 4; fm++)
                af[fm] = *(const bf16x8*)(As + (wr * 64 + fm * 16 + c) * 64 + ks * 32 + g * 8);
            #pragma unroll
            for (int fn = 0; fn < 4; fn++)
                bfr[fn] = *(const bf16x8*)(Bs + (wc * 64 + fn * 16 + c) * 64 + ks * 32 + g * 8);
            #pragma unroll
            for (int fm = 0; fm < 4; fm++)
                #pragma unroll
                for (int fn = 0; fn < 4; fn++)
                    acc[fm][fn] = mfma16(af[fm], bfr[fn], acc[fm][fn]);
        }
    }
    #pragma unroll
    for (int fn = 0; fn < 4; fn++) {
        int n = nt * 128 + wc * 64 + fn * 16 + c;
        float bval = bo[n];
        #pragma unroll
        for (int fm = 0; fm < 4; fm++) {
            int mbase = mt * 128 + wr * 64 + fm * 16 + g * 4;
            #pragma unroll
            for (int i = 0; i < 4; i++)
                out[(size_t)(mbase + i) * INW + n] = acc[fm][fn][i] + bval;
        }
    }
}

// ---------------------------------------------------------------------------
// Kernel 4: out[:, 1024:1040] = mean over heads of Ctx[..., 64:80]
// ---------------------------------------------------------------------------
__global__ __launch_bounds__(256) void encmean_kernel(
    const short* __restrict__ Ctx, float* __restrict__ out)
{
    int idx = blockIdx.x * 256 + threadIdx.x;   // 65536 = NTOK*POSD
    int tok = idx >> 4, p = idx & 15;
    int b = tok >> 11, l = tok & 2047;
    float s = 0.f;
    #pragma unroll
    for (int h = 0; h < NH; h++)
        s += bf2f(Ctx[((size_t)(b * NH + h) * LEN + l) * DHE + DHD + p]);
    out[(size_t)tok * INW + DIM + p] = s * (1.0f / NH);
}

// ---------------------------------------------------------------------------
extern "C" void kernel_launch(void* const* d_in, const int* in_sizes, int n_in,
                              void* d_out, int out_size, void* d_ws, size_t ws_size,
                              hipStream_t stream)
{
    const float* qin = (const float*)d_in[0];
    const float* kin = (const float*)d_in[1];
    const float* vin = (const float*)d_in[2];
    const float* Wq  = (const float*)d_in[3];
    const float* bq  = (const float*)d_in[4];
    const float* Wk  = (const float*)d_in[5];
    const float* bk  = (const float*)d_in[6];
    const float* Wv  = (const float*)d_in[7];
    const float* bv  = (const float*)d_in[8];
    const float* Wo  = (const float*)d_in[9];
    const float* bo  = (const float*)d_in[10];
    float* out = (float*)d_out;

    short* X16 = (short*)d_ws;                       // 3*NTOK*DIM
    short* W16 = X16 + (size_t)3 * NTOK * DIM;       // 4*DIM*DIM
    short* Qb  = W16 + (size_t)4 * DIM * DIM;        // NTOK*DIM
    short* Kb  = Qb  + (size_t)NTOK * DIM;           // NTOK*DIM
    short* Vt  = Kb  + (size_t)NTOK * DIM;           // BS*NH*DHE*LEN
    short* Ctx = Vt  + (size_t)BS * NH * DHE * LEN;  // BS*NH*LEN*DHE

    prep_kernel<<<16896, 256, 0, stream>>>(qin, kin, vin, Wq, Wk, Wv, Wo, X16, W16, Vt);
    qkv_gemm<<<768, 256, 0, stream>>>(X16, W16, bq, bk, bv, Qb, Kb, Vt);
    attn_kernel<<<1024, 256, 0, stream>>>(Qb, Kb, Vt, Ctx);
    out_gemm<<<256, 256, 0, stream>>>(Ctx, W16 + (size_t)3 * DIM * DIM, bo, out);
    encmean_kernel<<<256, 256, 0, stream>>>(Ctx, out);
}